// Round 5
// baseline (933.329 us; speedup 1.0000x reference)
//
#include <hip/hip_runtime.h>
#include <hip/hip_bf16.h>

// GCN 2-layer forward. CSR pull aggregation with XCD-replicated histograms AND
// replica-segmented CSR (each XCD writes only its own contiguous csr region).
// x[N,128] f32, src[E], dst[E] i32, W1[128,64], b1[64], W2[64,8], b2[8]
// out: softmax probs [N,8] f32.

#define IN_DIM 128
#define HID 64
#define NC 8
#define REP 8        // replica per XCD; blockIdx & 7 ~ XCD under round-robin dispatch
#define XS_LD 132    // padded leading dim for x tile in LDS

// replicated degree histograms: replica r = blockIdx & 7 keeps atomics inside one XCD's L2
__global__ void hist_k(const int* __restrict__ src, const int* __restrict__ dst,
                       int* __restrict__ cout_, int* __restrict__ cin_, int e, int n) {
    int i = blockIdx.x * blockDim.x + threadIdx.x;
    int r = blockIdx.x & (REP - 1);
    if (i < e) {
        atomicAdd(&cout_[r * n + src[i]], 1);
        atomicAdd(&cin_[r * n + dst[i]], 1);
    }
}

// degrees -> rsqrt norms (counts stay intact; agg kernels use cin_ as segment lengths)
__global__ void reduce_k(const int* __restrict__ cin_, const int* __restrict__ cout_,
                         float* __restrict__ out_norm, float* __restrict__ in_norm, int n) {
    int v = blockIdx.x * blockDim.x + threadIdx.x;
    if (v >= n) return;
    int ind = 0, outd = 0;
#pragma unroll
    for (int r = 0; r < REP; ++r) {
        ind  += cin_[r * n + v];
        outd += cout_[r * n + v];
    }
    in_norm[v]  = rsqrtf(fmaxf((float)ind, 1.0f));
    out_norm[v] = rsqrtf(fmaxf((float)outd, 1.0f));
}

// per-replica block sums of cin_ (grid.y = replica)
__global__ void scanA2(const int* __restrict__ cin_, int* __restrict__ bsum, int n, int nb) {
    int r = blockIdx.y;
    int t = threadIdx.x;
    int i = blockIdx.x * 256 + t;
    int v = (i < n) ? cin_[r * n + i] : 0;
#pragma unroll
    for (int d = 1; d < 64; d <<= 1) v += __shfl_xor(v, d, 64);
    __shared__ int w4[4];
    if ((t & 63) == 0) w4[t >> 6] = v;
    __syncthreads();
    if (t == 0) bsum[r * nb + blockIdx.x] = w4[0] + w4[1] + w4[2] + w4[3];
}

// per-replica exclusive scan of block sums + deterministic replica base offset.
// replica r's edge count is fixed by the grid mapping: edges i with ((i>>8)&7)==r.
__global__ void scanB2(int* __restrict__ bsum, int nb, int e) {
    int r = blockIdx.x;
    int total_blocks = (e + 255) >> 8;
    int rem = e & 255;                     // edges in last block (0 => full)
    int last = total_blocks - 1;
    int base = 0;
    for (int q = 0; q < r; ++q) {
        int cnt = (q < total_blocks) ? ((total_blocks - 1 - q) / 8 + 1) : 0;
        int edges = cnt << 8;
        if (rem != 0 && (last & 7) == q) edges -= (256 - rem);
        base += edges;
    }
    __shared__ int s[512];
    int t = threadIdx.x;
    s[t] = (t < nb) ? bsum[r * nb + t] : 0;
    __syncthreads();
    for (int d = 1; d < 512; d <<= 1) {
        int v = (t >= d) ? s[t - d] : 0;
        __syncthreads();
        s[t] += v;
        __syncthreads();
    }
    if (t < nb) bsum[r * nb + t] = base + (t ? s[t - 1] : 0);
}

// per-block exclusive scan -> per-(replica,node) segment starts; init cursors
__global__ void scanC2(const int* __restrict__ cin_, const int* __restrict__ bsum,
                       int* __restrict__ segptr, int* __restrict__ cursor, int n, int nb) {
    int r = blockIdx.y;
    __shared__ int s[256];
    int t = threadIdx.x;
    int i = blockIdx.x * 256 + t;
    int v = (i < n) ? cin_[r * n + i] : 0;
    s[t] = v;
    __syncthreads();
    for (int d = 1; d < 256; d <<= 1) {
        int u = (t >= d) ? s[t - d] : 0;
        __syncthreads();
        s[t] += u;
        __syncthreads();
    }
    if (i < n) {
        int ex = bsum[r * nb + blockIdx.x] + s[t] - v;
        segptr[r * n + i] = ex;
        cursor[r * n + i] = ex;
    }
}

// scatter edge sources into replica-local CSR region (XCD-local atomics AND stores)
__global__ void fill_k(const int* __restrict__ src, const int* __restrict__ dst,
                       int* __restrict__ cursor, int* __restrict__ csr, int e, int n) {
    int i = blockIdx.x * blockDim.x + threadIdx.x;
    int r = blockIdx.x & (REP - 1);
    if (i < e) {
        int d = dst[i];
        int slot = atomicAdd(&cursor[r * n + d], 1);
        csr[slot] = src[i];
    }
}

// h0[i][j] = out_norm[i] * (x[i] @ W1)[j]; 64x64 tile, 4x4 per thread
__global__ __launch_bounds__(256) void gemm1_k(const float* __restrict__ x, const float* __restrict__ W1,
                        const float* __restrict__ out_norm, float* __restrict__ h0, int n) {
    __shared__ float xs[64 * XS_LD];
    __shared__ float Ws[IN_DIM * HID];
    int t = threadIdx.x;
    int row0 = blockIdx.x * 64;
#pragma unroll
    for (int j = 0; j < 8; ++j) {
        int f4 = t + j * 256;
        *(float4*)&Ws[f4 * 4] = ((const float4*)W1)[f4];
    }
#pragma unroll
    for (int j = 0; j < 8; ++j) {
        int f4 = t + j * 256;
        int r = f4 >> 5;
        int k = (f4 & 31) * 4;
        float4 v = (row0 + r < n) ? ((const float4*)x)[(size_t)(row0 + r) * 32 + (f4 & 31)]
                                  : make_float4(0.f, 0.f, 0.f, 0.f);
        *(float4*)&xs[r * XS_LD + k] = v;
    }
    __syncthreads();
    int rq = (t >> 4) * 4;
    int cq = (t & 15) * 4;
    float acc[4][4] = {};
    for (int k = 0; k < IN_DIM; k += 4) {
        float4 xr[4], wc[4];
#pragma unroll
        for (int i = 0; i < 4; ++i) xr[i] = *(const float4*)&xs[(rq + i) * XS_LD + k];
#pragma unroll
        for (int kk = 0; kk < 4; ++kk) wc[kk] = *(const float4*)&Ws[(k + kk) * HID + cq];
#pragma unroll
        for (int i = 0; i < 4; ++i) {
            float xv0 = xr[i].x, xv1 = xr[i].y, xv2 = xr[i].z, xv3 = xr[i].w;
            acc[i][0] += xv0 * wc[0].x + xv1 * wc[1].x + xv2 * wc[2].x + xv3 * wc[3].x;
            acc[i][1] += xv0 * wc[0].y + xv1 * wc[1].y + xv2 * wc[2].y + xv3 * wc[3].y;
            acc[i][2] += xv0 * wc[0].z + xv1 * wc[1].z + xv2 * wc[2].z + xv3 * wc[3].z;
            acc[i][3] += xv0 * wc[0].w + xv1 * wc[1].w + xv2 * wc[2].w + xv3 * wc[3].w;
        }
    }
#pragma unroll
    for (int i = 0; i < 4; ++i) {
        int row = row0 + rq + i;
        if (row < n) {
            float onn = out_norm[row];
            float4 o = make_float4(acc[i][0] * onn, acc[i][1] * onn, acc[i][2] * onn, acc[i][3] * onn);
            *(float4*)&h0[(size_t)row * HID + cq] = o;
        }
    }
}

// wave per dst node: pull-aggregate h0 rows over 8 replica segments,
// then relu/norm/bias + W2 projection via cross-lane reductions.
__global__ void agg1proj_k(const int* __restrict__ segptr, const int* __restrict__ cnt,
                           const int* __restrict__ csr, const float* __restrict__ h0,
                           const float* __restrict__ in_norm, const float* __restrict__ out_norm,
                           const float* __restrict__ b1, const float* __restrict__ W2,
                           float* __restrict__ h2p, int n) {
    int wid = (blockIdx.x * blockDim.x + threadIdx.x) >> 6;
    int lane = threadIdx.x & 63;
    if (wid >= n) return;
    float acc = 0.f;
#pragma unroll
    for (int r = 0; r < REP; ++r) {
        int beg = segptr[r * n + wid];
        int end = beg + cnt[r * n + wid];
        int j = beg;
        for (; j + 4 <= end; j += 4) {
            int s0 = csr[j], s1 = csr[j + 1], s2 = csr[j + 2], s3 = csr[j + 3];
            acc += h0[(size_t)s0 * HID + lane];
            acc += h0[(size_t)s1 * HID + lane];
            acc += h0[(size_t)s2 * HID + lane];
            acc += h0[(size_t)s3 * HID + lane];
        }
        for (; j < end; ++j) acc += h0[(size_t)csr[j] * HID + lane];
    }
    float v = fmaxf(acc * in_norm[wid] + b1[lane], 0.f);
    float onn = out_norm[wid];
    float res = 0.f;
#pragma unroll
    for (int c = 0; c < NC; ++c) {
        float p = v * W2[lane * NC + c];
        p += __shfl_xor(p, 1, 64);
        p += __shfl_xor(p, 2, 64);
        p += __shfl_xor(p, 4, 64);
        p += __shfl_xor(p, 8, 64);
        p += __shfl_xor(p, 16, 64);
        p += __shfl_xor(p, 32, 64);
        if (lane == c) res = p;
    }
    if (lane < NC) h2p[(size_t)wid * NC + lane] = onn * res;
}

// wave per dst node: pull-aggregate h2p rows over 8 replica segments, bias + softmax
__global__ void agg2smax_k(const int* __restrict__ segptr, const int* __restrict__ cnt,
                           const int* __restrict__ csr, const float* __restrict__ h2p,
                           const float* __restrict__ in_norm, const float* __restrict__ b2,
                           float* __restrict__ out, int n) {
    int wid = (blockIdx.x * blockDim.x + threadIdx.x) >> 6;
    int lane = threadIdx.x & 63;
    if (wid >= n) return;
    int c = lane & 7, e8 = lane >> 3;
    float acc = 0.f;
#pragma unroll
    for (int r = 0; r < REP; ++r) {
        int beg = segptr[r * n + wid];
        int end = beg + cnt[r * n + wid];
        for (int j = beg + e8; j < end; j += 8) {
            acc += h2p[(size_t)csr[j] * NC + c];
        }
    }
    acc += __shfl_xor(acc, 8, 64);
    acc += __shfl_xor(acc, 16, 64);
    acc += __shfl_xor(acc, 32, 64);
    float v = acc * in_norm[wid] + b2[c];
    float m = v;
    m = fmaxf(m, __shfl_xor(m, 1, 64));
    m = fmaxf(m, __shfl_xor(m, 2, 64));
    m = fmaxf(m, __shfl_xor(m, 4, 64));
    float ev = __expf(v - m);
    float s8 = ev;
    s8 += __shfl_xor(s8, 1, 64);
    s8 += __shfl_xor(s8, 2, 64);
    s8 += __shfl_xor(s8, 4, 64);
    if (e8 == 0) out[(size_t)wid * NC + c] = ev / s8;
}

extern "C" void kernel_launch(void* const* d_in, const int* in_sizes, int n_in,
                              void* d_out, int out_size, void* d_ws, size_t ws_size,
                              hipStream_t stream) {
    const float* x   = (const float*)d_in[0];
    const int*   src = (const int*)d_in[1];
    const int*   dst = (const int*)d_in[2];
    const float* W1  = (const float*)d_in[3];
    const float* b1  = (const float*)d_in[4];
    const float* W2  = (const float*)d_in[5];
    const float* b2  = (const float*)d_in[6];
    float* out = (float*)d_out;

    const int N = in_sizes[0] / IN_DIM;   // 100000
    const int E = in_sizes[1];            // 3200000
    const int NB = (N + 255) / 256;       // 391 (<= 512)

    float* ws = (float*)d_ws;
    float* out_norm = ws;                            // N
    float* in_norm  = ws + (size_t)N;                // N
    float* h0       = ws + (size_t)2 * N;            // 64N
    float* h2p      = ws + (size_t)66 * N;           // 8N
    int*   cin      = (int*)(ws + (size_t)74 * N);   // 8N (segment lengths, kept)
    int*   cout_    = cin + (size_t)REP * N;         // 8N
    int*   cursor   = cout_ + (size_t)REP * N;       // 8N
    int*   segptr   = cursor + (size_t)REP * N;      // 8N
    int*   bsum     = segptr + (size_t)REP * N;      // REP*NB
    int*   csr      = bsum + (size_t)REP * NB;       // E
    // total ~ 29.6 MB floats + ~26 MB ints

    hipMemsetAsync(cin, 0, (size_t)2 * REP * N * sizeof(int), stream);

    hist_k<<<(E + 255) / 256, 256, 0, stream>>>(src, dst, cout_, cin, E, N);
    reduce_k<<<(N + 255) / 256, 256, 0, stream>>>(cin, cout_, out_norm, in_norm, N);
    scanA2<<<dim3(NB, REP), 256, 0, stream>>>(cin, bsum, N, NB);
    scanB2<<<REP, 512, 0, stream>>>(bsum, NB, E);
    scanC2<<<dim3(NB, REP), 256, 0, stream>>>(cin, bsum, segptr, cursor, N, NB);
    fill_k<<<(E + 255) / 256, 256, 0, stream>>>(src, dst, cursor, csr, E, N);
    gemm1_k<<<(N + 63) / 64, 256, 0, stream>>>(x, W1, out_norm, h0, N);
    agg1proj_k<<<(N + 3) / 4, 256, 0, stream>>>(segptr, cin, csr, h0, in_norm, out_norm, b1, W2, h2p, N);
    agg2smax_k<<<(N + 3) / 4, 256, 0, stream>>>(segptr, cin, csr, h2p, in_norm, b2, out, N);
}

// Round 8
// 556.309 us; speedup vs baseline: 1.6777x; 1.6777x over previous
//
#include <hip/hip_runtime.h>
#include <hip/hip_bf16.h>

// GCN 2-layer forward. Atomic-free CSR build:
//   per-block LDS histograms -> dense per-block counts -> reduce/scan -> LDS-cursor fill.
// Aggregation: pull-style over single contiguous per-node CSR ranges.
// x[N,128] f32, src[E], dst[E] i32, W1[128,64], b1[64], W2[64,8], b2[8]
// out: softmax probs [N,8] f32.

#define IN_DIM 128
#define HID 64
#define NC 8
#define BH 128        // count columns = histogram/fill blocks
#define TPB 1024
#define BINS 33792    // 132 KB LDS; ceil(100000/33792) = 3 range passes
#define XS_LD 132     // padded leading dim for x tile in LDS

// per-block LDS histogram over key ranges, dense flush (NO global atomics)
__global__ __launch_bounds__(TPB) void histcnt_k(const int* __restrict__ keys,
                                                 int* __restrict__ cnt, int e, int n) {
    __shared__ int bins[BINS];
    int b = blockIdx.x;
    int chunk = (e + gridDim.x - 1) / gridDim.x;
    int beg = b * chunk, end = min(e, beg + chunk);
    for (int rb = 0; rb < n; rb += BINS) {
        int hi = min(n - rb, BINS);
        for (int i = threadIdx.x; i < hi; i += TPB) bins[i] = 0;
        __syncthreads();
        for (int i = beg + threadIdx.x; i < end; i += TPB) {
            int k = keys[i] - rb;
            if ((unsigned)k < (unsigned)hi) atomicAdd(&bins[k], 1);
        }
        __syncthreads();
        for (int i = threadIdx.x; i < hi; i += TPB)
            cnt[(size_t)b * n + rb + i] = bins[i];
        __syncthreads();
    }
}

// sum count columns -> out_norm (run after histcnt on src)
__global__ void redout_k(const int* __restrict__ cnt, float* __restrict__ out_norm, int n) {
    int v = blockIdx.x * blockDim.x + threadIdx.x;
    if (v >= n) return;
    int s = 0;
    for (int b = 0; b < BH; ++b) s += cnt[(size_t)b * n + v];
    out_norm[v] = rsqrtf(fmaxf((float)s, 1.0f));
}

// in counts -> indeg + in_norm; rewrite cnt in place as per-block exclusive bases
__global__ void redin_k(int* __restrict__ cnt, float* __restrict__ in_norm,
                        int* __restrict__ indeg, int n) {
    int v = blockIdx.x * blockDim.x + threadIdx.x;
    if (v >= n) return;
    int run = 0;
    for (int b = 0; b < BH; ++b) {
        size_t idx = (size_t)b * n + v;
        int c = cnt[idx];
        cnt[idx] = run;
        run += c;
    }
    indeg[v] = run;
    in_norm[v] = rsqrtf(fmaxf((float)run, 1.0f));
}

// block sums of in-degree
__global__ void scanA(const int* __restrict__ indeg, int* __restrict__ bsum, int n) {
    int t = threadIdx.x;
    int i = blockIdx.x * 256 + t;
    int v = (i < n) ? indeg[i] : 0;
#pragma unroll
    for (int d = 1; d < 64; d <<= 1) v += __shfl_xor(v, d, 64);
    __shared__ int w4[4];
    if ((t & 63) == 0) w4[t >> 6] = v;
    __syncthreads();
    if (t == 0) bsum[blockIdx.x] = w4[0] + w4[1] + w4[2] + w4[3];
}

// exclusive scan of block sums (nb <= 512), writes rowptr[n] = E
__global__ void scanB(int* __restrict__ bsum, int nb, int* __restrict__ rowptr, int n) {
    __shared__ int s[512];
    int t = threadIdx.x;
    s[t] = (t < nb) ? bsum[t] : 0;
    __syncthreads();
    for (int d = 1; d < 512; d <<= 1) {
        int v = (t >= d) ? s[t - d] : 0;
        __syncthreads();
        s[t] += v;
        __syncthreads();
    }
    if (t < nb) bsum[t] = t ? s[t - 1] : 0;
    if (t == 0) rowptr[n] = s[nb - 1];
}

// per-block exclusive scan + block offset -> rowptr
__global__ void scanC(const int* __restrict__ indeg, const int* __restrict__ bsum,
                      int* __restrict__ rowptr, int n) {
    __shared__ int s[256];
    int t = threadIdx.x;
    int i = blockIdx.x * 256 + t;
    int v = (i < n) ? indeg[i] : 0;
    s[t] = v;
    __syncthreads();
    for (int d = 1; d < 256; d <<= 1) {
        int u = (t >= d) ? s[t - d] : 0;
        __syncthreads();
        s[t] += u;
        __syncthreads();
    }
    if (i < n) rowptr[i] = bsum[blockIdx.x] + s[t] - v;
}

// CSR fill: LDS cursor table per range pass; slot = rowptr + per-block base + lds_cursor++.
// Globally atomic-free (only LDS atomics).
__global__ __launch_bounds__(TPB) void fill2_k(const int* __restrict__ src, const int* __restrict__ dst,
                        const int* __restrict__ rowptr, const int* __restrict__ base,
                        int* __restrict__ csr, int e, int n) {
    __shared__ int cur[BINS];
    int b = blockIdx.x;
    int chunk = (e + gridDim.x - 1) / gridDim.x;
    int beg = b * chunk, end = min(e, beg + chunk);
    for (int rb = 0; rb < n; rb += BINS) {
        int hi = min(n - rb, BINS);
        for (int i = threadIdx.x; i < hi; i += TPB) cur[i] = 0;
        __syncthreads();
        for (int i = beg + threadIdx.x; i < end; i += TPB) {
            int d = dst[i];
            int dl = d - rb;
            if ((unsigned)dl < (unsigned)hi) {
                int slot = rowptr[d] + base[(size_t)b * n + d] + atomicAdd(&cur[dl], 1);
                csr[slot] = src[i];
            }
        }
        __syncthreads();
    }
}

// h0[i][j] = out_norm[i] * (x[i] @ W1)[j]; 64x64 tile, 4x4 per thread
__global__ __launch_bounds__(256) void gemm1_k(const float* __restrict__ x, const float* __restrict__ W1,
                        const float* __restrict__ out_norm, float* __restrict__ h0, int n) {
    __shared__ float xs[64 * XS_LD];
    __shared__ float Ws[IN_DIM * HID];
    int t = threadIdx.x;
    int row0 = blockIdx.x * 64;
#pragma unroll
    for (int j = 0; j < 8; ++j) {
        int f4 = t + j * 256;
        *(float4*)&Ws[f4 * 4] = ((const float4*)W1)[f4];
    }
#pragma unroll
    for (int j = 0; j < 8; ++j) {
        int f4 = t + j * 256;
        int r = f4 >> 5;
        int k = (f4 & 31) * 4;
        float4 v = (row0 + r < n) ? ((const float4*)x)[(size_t)(row0 + r) * 32 + (f4 & 31)]
                                  : make_float4(0.f, 0.f, 0.f, 0.f);
        *(float4*)&xs[r * XS_LD + k] = v;
    }
    __syncthreads();
    int rq = (t >> 4) * 4;
    int cq = (t & 15) * 4;
    float acc[4][4] = {};
    for (int k = 0; k < IN_DIM; k += 4) {
        float4 xr[4], wc[4];
#pragma unroll
        for (int i = 0; i < 4; ++i) xr[i] = *(const float4*)&xs[(rq + i) * XS_LD + k];
#pragma unroll
        for (int kk = 0; kk < 4; ++kk) wc[kk] = *(const float4*)&Ws[(k + kk) * HID + cq];
#pragma unroll
        for (int i = 0; i < 4; ++i) {
            float xv0 = xr[i].x, xv1 = xr[i].y, xv2 = xr[i].z, xv3 = xr[i].w;
            acc[i][0] += xv0 * wc[0].x + xv1 * wc[1].x + xv2 * wc[2].x + xv3 * wc[3].x;
            acc[i][1] += xv0 * wc[0].y + xv1 * wc[1].y + xv2 * wc[2].y + xv3 * wc[3].y;
            acc[i][2] += xv0 * wc[0].z + xv1 * wc[1].z + xv2 * wc[2].z + xv3 * wc[3].z;
            acc[i][3] += xv0 * wc[0].w + xv1 * wc[1].w + xv2 * wc[2].w + xv3 * wc[3].w;
        }
    }
#pragma unroll
    for (int i = 0; i < 4; ++i) {
        int row = row0 + rq + i;
        if (row < n) {
            float onn = out_norm[row];
            float4 o = make_float4(acc[i][0] * onn, acc[i][1] * onn, acc[i][2] * onn, acc[i][3] * onn);
            *(float4*)&h0[(size_t)row * HID + cq] = o;
        }
    }
}

// wave per dst node: pull-aggregate h0 rows over ONE contiguous range,
// then relu/norm/bias + W2 projection via cross-lane reductions.
__global__ void agg1proj_k(const int* __restrict__ rowptr, const int* __restrict__ csr,
                           const float* __restrict__ h0, const float* __restrict__ in_norm,
                           const float* __restrict__ out_norm, const float* __restrict__ b1,
                           const float* __restrict__ W2, float* __restrict__ h2p, int n) {
    int wid = (blockIdx.x * blockDim.x + threadIdx.x) >> 6;
    int lane = threadIdx.x & 63;
    if (wid >= n) return;
    int beg = rowptr[wid], end = rowptr[wid + 1];
    float acc = 0.f;
    int j = beg;
    for (; j + 4 <= end; j += 4) {
        int s0 = csr[j], s1 = csr[j + 1], s2 = csr[j + 2], s3 = csr[j + 3];
        acc += h0[(size_t)s0 * HID + lane];
        acc += h0[(size_t)s1 * HID + lane];
        acc += h0[(size_t)s2 * HID + lane];
        acc += h0[(size_t)s3 * HID + lane];
    }
    for (; j < end; ++j) acc += h0[(size_t)csr[j] * HID + lane];
    float v = fmaxf(acc * in_norm[wid] + b1[lane], 0.f);
    float onn = out_norm[wid];
    float res = 0.f;
#pragma unroll
    for (int c = 0; c < NC; ++c) {
        float p = v * W2[lane * NC + c];
        p += __shfl_xor(p, 1, 64);
        p += __shfl_xor(p, 2, 64);
        p += __shfl_xor(p, 4, 64);
        p += __shfl_xor(p, 8, 64);
        p += __shfl_xor(p, 16, 64);
        p += __shfl_xor(p, 32, 64);
        if (lane == c) res = p;
    }
    if (lane < NC) h2p[(size_t)wid * NC + lane] = onn * res;
}

// wave per dst node: pull-aggregate h2p rows, bias + softmax
__global__ void agg2smax_k(const int* __restrict__ rowptr, const int* __restrict__ csr,
                           const float* __restrict__ h2p, const float* __restrict__ in_norm,
                           const float* __restrict__ b2, float* __restrict__ out, int n) {
    int wid = (blockIdx.x * blockDim.x + threadIdx.x) >> 6;
    int lane = threadIdx.x & 63;
    if (wid >= n) return;
    int beg = rowptr[wid], end = rowptr[wid + 1];
    int c = lane & 7, e8 = lane >> 3;
    float acc = 0.f;
    for (int j = beg + e8; j < end; j += 8) {
        acc += h2p[(size_t)csr[j] * NC + c];
    }
    acc += __shfl_xor(acc, 8, 64);
    acc += __shfl_xor(acc, 16, 64);
    acc += __shfl_xor(acc, 32, 64);
    float v = acc * in_norm[wid] + b2[c];
    float m = v;
    m = fmaxf(m, __shfl_xor(m, 1, 64));
    m = fmaxf(m, __shfl_xor(m, 2, 64));
    m = fmaxf(m, __shfl_xor(m, 4, 64));
    float ev = __expf(v - m);
    float s8 = ev;
    s8 += __shfl_xor(s8, 1, 64);
    s8 += __shfl_xor(s8, 2, 64);
    s8 += __shfl_xor(s8, 4, 64);
    if (e8 == 0) out[(size_t)wid * NC + c] = ev / s8;
}

extern "C" void kernel_launch(void* const* d_in, const int* in_sizes, int n_in,
                              void* d_out, int out_size, void* d_ws, size_t ws_size,
                              hipStream_t stream) {
    const float* x   = (const float*)d_in[0];
    const int*   src = (const int*)d_in[1];
    const int*   dst = (const int*)d_in[2];
    const float* W1  = (const float*)d_in[3];
    const float* b1  = (const float*)d_in[4];
    const float* W2  = (const float*)d_in[5];
    const float* b2  = (const float*)d_in[6];
    float* out = (float*)d_out;

    const int N = in_sizes[0] / IN_DIM;   // 100000
    const int E = in_sizes[1];            // 3200000
    const int NB = (N + 255) / 256;       // 391 (<= 512)

    // layout: small stuff, csr, then big region (cnt during build, h0+h2p after).
    float* ws = (float*)d_ws;
    float* out_norm = ws;                            // N
    float* in_norm  = ws + (size_t)N;                // N
    int*   indeg    = (int*)(ws + (size_t)2 * N);    // N
    int*   rowptr   = indeg + N;                     // N+1
    int*   bsum     = rowptr + (N + 1);              // 512
    int*   csr      = bsum + 512;                    // E
    int*   cnt      = csr + E;                       // BH*N ints (51.2 MB), dead after fill
    float* h0       = (float*)cnt;                   // 64N floats  (aliases cnt)
    float* h2p      = (float*)cnt + (size_t)64 * N;  // 8N floats   (72N <= 128N ok)
    // total ~ 65 MB

    // 1. out-degree counts -> out_norm (cnt buffer pass 1)
    histcnt_k<<<BH, TPB, 0, stream>>>(src, cnt, E, N);
    redout_k<<<(N + 255) / 256, 256, 0, stream>>>(cnt, out_norm, N);
    // 2. in-degree counts -> indeg, in_norm, per-block bases (cnt buffer pass 2)
    histcnt_k<<<BH, TPB, 0, stream>>>(dst, cnt, E, N);
    redin_k<<<(N + 255) / 256, 256, 0, stream>>>(cnt, in_norm, indeg, N);
    // 3. rowptr = exclusive scan(indeg)
    scanA<<<NB, 256, 0, stream>>>(indeg, bsum, N);
    scanB<<<1, 512, 0, stream>>>(bsum, NB, rowptr, N);
    scanC<<<NB, 256, 0, stream>>>(indeg, bsum, rowptr, N);
    // 4. CSR fill (LDS cursors; no global atomics)
    fill2_k<<<BH, TPB, 0, stream>>>(src, dst, rowptr, cnt, csr, E, N);
    // 5. dense compute (cnt region now reused as h0/h2p)
    gemm1_k<<<(N + 63) / 64, 256, 0, stream>>>(x, W1, out_norm, h0, N);
    agg1proj_k<<<(N + 3) / 4, 256, 0, stream>>>(rowptr, csr, h0, in_norm, out_norm, b1, W2, h2p, N);
    agg2smax_k<<<(N + 3) / 4, 256, 0, stream>>>(rowptr, csr, h2p, in_norm, b2, out, N);
}

// Round 11
// 547.385 us; speedup vs baseline: 1.7051x; 1.0163x over previous
//
#include <hip/hip_runtime.h>
#include <hip/hip_bf16.h>

// GCN 2-layer forward. Atomic-free CSR build:
//   per-block LDS histograms -> dense per-block counts -> reduce/scan -> LDS-cursor fill.
// Aggregation: pull-style, 8-deep independent gather unroll (MLP fix, round 8).
// x[N,128] f32, src[E], dst[E] i32, W1[128,64], b1[64], W2[64,8], b2[8]
// out: softmax probs [N,8] f32.

#define IN_DIM 128
#define HID 64
#define NC 8
#define BH 128        // count columns = histogram/fill blocks
#define TPB 1024
#define BINS 33792    // 132 KB LDS; ceil(100000/33792) = 3 range passes
#define XS_LD 132     // padded leading dim for x tile in LDS

// per-block LDS histogram over key ranges, dense flush (NO global atomics)
__global__ __launch_bounds__(TPB) void histcnt_k(const int* __restrict__ keys,
                                                 int* __restrict__ cnt, int e, int n) {
    __shared__ int bins[BINS];
    int b = blockIdx.x;
    int chunk = (e + gridDim.x - 1) / gridDim.x;
    int beg = b * chunk, end = min(e, beg + chunk);
    for (int rb = 0; rb < n; rb += BINS) {
        int hi = min(n - rb, BINS);
        for (int i = threadIdx.x; i < hi; i += TPB) bins[i] = 0;
        __syncthreads();
        for (int i = beg + threadIdx.x; i < end; i += TPB) {
            int k = keys[i] - rb;
            if ((unsigned)k < (unsigned)hi) atomicAdd(&bins[k], 1);
        }
        __syncthreads();
        for (int i = threadIdx.x; i < hi; i += TPB)
            cnt[(size_t)b * n + rb + i] = bins[i];
        __syncthreads();
    }
}

// sum count columns -> out_norm (run after histcnt on src)
__global__ void redout_k(const int* __restrict__ cnt, float* __restrict__ out_norm, int n) {
    int v = blockIdx.x * blockDim.x + threadIdx.x;
    if (v >= n) return;
    int s = 0;
    for (int b = 0; b < BH; ++b) s += cnt[(size_t)b * n + v];
    out_norm[v] = rsqrtf(fmaxf((float)s, 1.0f));
}

// in counts -> indeg + in_norm; rewrite cnt in place as per-block exclusive bases
__global__ void redin_k(int* __restrict__ cnt, float* __restrict__ in_norm,
                        int* __restrict__ indeg, int n) {
    int v = blockIdx.x * blockDim.x + threadIdx.x;
    if (v >= n) return;
    int run = 0;
    for (int b = 0; b < BH; ++b) {
        size_t idx = (size_t)b * n + v;
        int c = cnt[idx];
        cnt[idx] = run;
        run += c;
    }
    indeg[v] = run;
    in_norm[v] = rsqrtf(fmaxf((float)run, 1.0f));
}

// block sums of in-degree
__global__ void scanA(const int* __restrict__ indeg, int* __restrict__ bsum, int n) {
    int t = threadIdx.x;
    int i = blockIdx.x * 256 + t;
    int v = (i < n) ? indeg[i] : 0;
#pragma unroll
    for (int d = 1; d < 64; d <<= 1) v += __shfl_xor(v, d, 64);
    __shared__ int w4[4];
    if ((t & 63) == 0) w4[t >> 6] = v;
    __syncthreads();
    if (t == 0) bsum[blockIdx.x] = w4[0] + w4[1] + w4[2] + w4[3];
}

// exclusive scan of block sums (nb <= 512), writes rowptr[n] = E
__global__ void scanB(int* __restrict__ bsum, int nb, int* __restrict__ rowptr, int n) {
    __shared__ int s[512];
    int t = threadIdx.x;
    s[t] = (t < nb) ? bsum[t] : 0;
    __syncthreads();
    for (int d = 1; d < 512; d <<= 1) {
        int v = (t >= d) ? s[t - d] : 0;
        __syncthreads();
        s[t] += v;
        __syncthreads();
    }
    if (t < nb) bsum[t] = t ? s[t - 1] : 0;
    if (t == 0) rowptr[n] = s[nb - 1];
}

// per-block exclusive scan + block offset -> rowptr
__global__ void scanC(const int* __restrict__ indeg, const int* __restrict__ bsum,
                      int* __restrict__ rowptr, int n) {
    __shared__ int s[256];
    int t = threadIdx.x;
    int i = blockIdx.x * 256 + t;
    int v = (i < n) ? indeg[i] : 0;
    s[t] = v;
    __syncthreads();
    for (int d = 1; d < 256; d <<= 1) {
        int u = (t >= d) ? s[t - d] : 0;
        __syncthreads();
        s[t] += u;
        __syncthreads();
    }
    if (i < n) rowptr[i] = bsum[blockIdx.x] + s[t] - v;
}

// CSR fill: LDS cursor table per range pass; slot = rowptr + per-block base + lds_cursor++.
// Globally atomic-free (only LDS atomics).
__global__ __launch_bounds__(TPB) void fill2_k(const int* __restrict__ src, const int* __restrict__ dst,
                        const int* __restrict__ rowptr, const int* __restrict__ base,
                        int* __restrict__ csr, int e, int n) {
    __shared__ int cur[BINS];
    int b = blockIdx.x;
    int chunk = (e + gridDim.x - 1) / gridDim.x;
    int beg = b * chunk, end = min(e, beg + chunk);
    for (int rb = 0; rb < n; rb += BINS) {
        int hi = min(n - rb, BINS);
        for (int i = threadIdx.x; i < hi; i += TPB) cur[i] = 0;
        __syncthreads();
        for (int i = beg + threadIdx.x; i < end; i += TPB) {
            int d = dst[i];
            int dl = d - rb;
            if ((unsigned)dl < (unsigned)hi) {
                int slot = rowptr[d] + base[(size_t)b * n + d] + atomicAdd(&cur[dl], 1);
                csr[slot] = src[i];
            }
        }
        __syncthreads();
    }
}

// h0[i][j] = out_norm[i] * (x[i] @ W1)[j]; 64x64 tile, 4x4 per thread
__global__ __launch_bounds__(256) void gemm1_k(const float* __restrict__ x, const float* __restrict__ W1,
                        const float* __restrict__ out_norm, float* __restrict__ h0, int n) {
    __shared__ float xs[64 * XS_LD];
    __shared__ float Ws[IN_DIM * HID];
    int t = threadIdx.x;
    int row0 = blockIdx.x * 64;
#pragma unroll
    for (int j = 0; j < 8; ++j) {
        int f4 = t + j * 256;
        *(float4*)&Ws[f4 * 4] = ((const float4*)W1)[f4];
    }
#pragma unroll
    for (int j = 0; j < 8; ++j) {
        int f4 = t + j * 256;
        int r = f4 >> 5;
        int k = (f4 & 31) * 4;
        float4 v = (row0 + r < n) ? ((const float4*)x)[(size_t)(row0 + r) * 32 + (f4 & 31)]
                                  : make_float4(0.f, 0.f, 0.f, 0.f);
        *(float4*)&xs[r * XS_LD + k] = v;
    }
    __syncthreads();
    int rq = (t >> 4) * 4;
    int cq = (t & 15) * 4;
    float acc[4][4] = {};
    for (int k = 0; k < IN_DIM; k += 4) {
        float4 xr[4], wc[4];
#pragma unroll
        for (int i = 0; i < 4; ++i) xr[i] = *(const float4*)&xs[(rq + i) * XS_LD + k];
#pragma unroll
        for (int kk = 0; kk < 4; ++kk) wc[kk] = *(const float4*)&Ws[(k + kk) * HID + cq];
#pragma unroll
        for (int i = 0; i < 4; ++i) {
            float xv0 = xr[i].x, xv1 = xr[i].y, xv2 = xr[i].z, xv3 = xr[i].w;
            acc[i][0] += xv0 * wc[0].x + xv1 * wc[1].x + xv2 * wc[2].x + xv3 * wc[3].x;
            acc[i][1] += xv0 * wc[0].y + xv1 * wc[1].y + xv2 * wc[2].y + xv3 * wc[3].y;
            acc[i][2] += xv0 * wc[0].z + xv1 * wc[1].z + xv2 * wc[2].z + xv3 * wc[3].z;
            acc[i][3] += xv0 * wc[0].w + xv1 * wc[1].w + xv2 * wc[2].w + xv3 * wc[3].w;
        }
    }
#pragma unroll
    for (int i = 0; i < 4; ++i) {
        int row = row0 + rq + i;
        if (row < n) {
            float onn = out_norm[row];
            float4 o = make_float4(acc[i][0] * onn, acc[i][1] * onn, acc[i][2] * onn, acc[i][3] * onn);
            *(float4*)&h0[(size_t)row * HID + cq] = o;
        }
    }
}

// wave per dst node: pull-aggregate h0 rows, 8 independent gathers in flight
// (latency/MLP fix), then relu/norm/bias + W2 projection via cross-lane reductions.
__global__ void agg1proj_k(const int* __restrict__ rowptr, const int* __restrict__ csr,
                           const float* __restrict__ h0, const float* __restrict__ in_norm,
                           const float* __restrict__ out_norm, const float* __restrict__ b1,
                           const float* __restrict__ W2, float* __restrict__ h2p, int n) {
    int wid = (blockIdx.x * blockDim.x + threadIdx.x) >> 6;
    int lane = threadIdx.x & 63;
    if (wid >= n) return;
    int beg = rowptr[wid], end = rowptr[wid + 1];
    float acc0 = 0.f, acc1 = 0.f, acc2 = 0.f, acc3 = 0.f;
    int j = beg;
    for (; j + 8 <= end; j += 8) {
        int s0 = csr[j],     s1 = csr[j + 1], s2 = csr[j + 2], s3 = csr[j + 3];
        int s4 = csr[j + 4], s5 = csr[j + 5], s6 = csr[j + 6], s7 = csr[j + 7];
        float a0 = h0[(size_t)s0 * HID + lane];
        float a1 = h0[(size_t)s1 * HID + lane];
        float a2 = h0[(size_t)s2 * HID + lane];
        float a3 = h0[(size_t)s3 * HID + lane];
        float a4 = h0[(size_t)s4 * HID + lane];
        float a5 = h0[(size_t)s5 * HID + lane];
        float a6 = h0[(size_t)s6 * HID + lane];
        float a7 = h0[(size_t)s7 * HID + lane];
        acc0 += a0; acc1 += a1; acc2 += a2; acc3 += a3;
        acc0 += a4; acc1 += a5; acc2 += a6; acc3 += a7;
    }
    if (j + 4 <= end) {
        int s0 = csr[j], s1 = csr[j + 1], s2 = csr[j + 2], s3 = csr[j + 3];
        acc0 += h0[(size_t)s0 * HID + lane];
        acc1 += h0[(size_t)s1 * HID + lane];
        acc2 += h0[(size_t)s2 * HID + lane];
        acc3 += h0[(size_t)s3 * HID + lane];
        j += 4;
    }
    for (; j < end; ++j) acc0 += h0[(size_t)csr[j] * HID + lane];
    float acc = (acc0 + acc1) + (acc2 + acc3);
    float v = fmaxf(acc * in_norm[wid] + b1[lane], 0.f);
    float onn = out_norm[wid];
    float res = 0.f;
#pragma unroll
    for (int c = 0; c < NC; ++c) {
        float p = v * W2[lane * NC + c];
        p += __shfl_xor(p, 1, 64);
        p += __shfl_xor(p, 2, 64);
        p += __shfl_xor(p, 4, 64);
        p += __shfl_xor(p, 8, 64);
        p += __shfl_xor(p, 16, 64);
        p += __shfl_xor(p, 32, 64);
        if (lane == c) res = p;
    }
    if (lane < NC) h2p[(size_t)wid * NC + lane] = onn * res;
}

// wave per dst node: pull-aggregate h2p rows (2-deep unroll), bias + softmax
__global__ void agg2smax_k(const int* __restrict__ rowptr, const int* __restrict__ csr,
                           const float* __restrict__ h2p, const float* __restrict__ in_norm,
                           const float* __restrict__ b2, float* __restrict__ out, int n) {
    int wid = (blockIdx.x * blockDim.x + threadIdx.x) >> 6;
    int lane = threadIdx.x & 63;
    if (wid >= n) return;
    int beg = rowptr[wid], end = rowptr[wid + 1];
    int c = lane & 7, e8 = lane >> 3;
    float acc0 = 0.f, acc1 = 0.f;
    int j = beg + e8;
    for (; j + 8 < end; j += 16) {
        int s0 = csr[j];
        int s1 = csr[j + 8];
        acc0 += h2p[(size_t)s0 * NC + c];
        acc1 += h2p[(size_t)s1 * NC + c];
    }
    for (; j < end; j += 8) acc0 += h2p[(size_t)csr[j] * NC + c];
    float acc = acc0 + acc1;
    acc += __shfl_xor(acc, 8, 64);
    acc += __shfl_xor(acc, 16, 64);
    acc += __shfl_xor(acc, 32, 64);
    float v = acc * in_norm[wid] + b2[c];
    float m = v;
    m = fmaxf(m, __shfl_xor(m, 1, 64));
    m = fmaxf(m, __shfl_xor(m, 2, 64));
    m = fmaxf(m, __shfl_xor(m, 4, 64));
    float ev = __expf(v - m);
    float s8 = ev;
    s8 += __shfl_xor(s8, 1, 64);
    s8 += __shfl_xor(s8, 2, 64);
    s8 += __shfl_xor(s8, 4, 64);
    if (e8 == 0) out[(size_t)wid * NC + c] = ev / s8;
}

extern "C" void kernel_launch(void* const* d_in, const int* in_sizes, int n_in,
                              void* d_out, int out_size, void* d_ws, size_t ws_size,
                              hipStream_t stream) {
    const float* x   = (const float*)d_in[0];
    const int*   src = (const int*)d_in[1];
    const int*   dst = (const int*)d_in[2];
    const float* W1  = (const float*)d_in[3];
    const float* b1  = (const float*)d_in[4];
    const float* W2  = (const float*)d_in[5];
    const float* b2  = (const float*)d_in[6];
    float* out = (float*)d_out;

    const int N = in_sizes[0] / IN_DIM;   // 100000
    const int E = in_sizes[1];            // 3200000
    const int NB = (N + 255) / 256;       // 391 (<= 512)

    // layout: small stuff, csr, then big region (cnt during build, h0+h2p after).
    float* ws = (float*)d_ws;
    float* out_norm = ws;                            // N
    float* in_norm  = ws + (size_t)N;                // N
    int*   indeg    = (int*)(ws + (size_t)2 * N);    // N
    int*   rowptr   = indeg + N;                     // N+1
    int*   bsum     = rowptr + (N + 1);              // 512
    int*   csr      = bsum + 512;                    // E
    int*   cnt      = csr + E;                       // BH*N ints (51.2 MB), dead after fill
    float* h0       = (float*)cnt;                   // 64N floats  (aliases cnt)
    float* h2p      = (float*)cnt + (size_t)64 * N;  // 8N floats   (72N <= 128N ok)
    // total ~ 65 MB

    // 1. out-degree counts -> out_norm (cnt buffer pass 1)
    histcnt_k<<<BH, TPB, 0, stream>>>(src, cnt, E, N);
    redout_k<<<(N + 255) / 256, 256, 0, stream>>>(cnt, out_norm, N);
    // 2. in-degree counts -> indeg, in_norm, per-block bases (cnt buffer pass 2)
    histcnt_k<<<BH, TPB, 0, stream>>>(dst, cnt, E, N);
    redin_k<<<(N + 255) / 256, 256, 0, stream>>>(cnt, in_norm, indeg, N);
    // 3. rowptr = exclusive scan(indeg)
    scanA<<<NB, 256, 0, stream>>>(indeg, bsum, N);
    scanB<<<1, 512, 0, stream>>>(bsum, NB, rowptr, N);
    scanC<<<NB, 256, 0, stream>>>(indeg, bsum, rowptr, N);
    // 4. CSR fill (LDS cursors; no global atomics)
    fill2_k<<<BH, TPB, 0, stream>>>(src, dst, rowptr, cnt, csr, E, N);
    // 5. dense compute (cnt region now reused as h0/h2p)
    gemm1_k<<<(N + 63) / 64, 256, 0, stream>>>(x, W1, out_norm, h0, N);
    agg1proj_k<<<(N + 3) / 4, 256, 0, stream>>>(rowptr, csr, h0, in_norm, out_norm, b1, W2, h2p, N);
    agg2smax_k<<<(N + 3) / 4, 256, 0, stream>>>(rowptr, csr, h2p, in_norm, b2, out, N);
}

// Round 14
// 472.634 us; speedup vs baseline: 1.9747x; 1.1582x over previous
//
#include <hip/hip_runtime.h>
#include <hip/hip_bf16.h>

// GCN 2-layer forward. Atomic-free CSR build (LDS histograms + LDS-cursor fill,
// cursors pre-loaded with per-block bases -> 1 random read/edge instead of 2).
// h0 stored as bf16 (f32 accum) to halve the layer-1 gather traffic.
// x[N,128] f32, src[E], dst[E] i32, W1[128,64], b1[64], W2[64,8], b2[8]
// out: softmax probs [N,8] f32.

#define IN_DIM 128
#define HID 64
#define NC 8
#define BH 128        // count columns = histogram/fill blocks
#define TPB 1024
#define BINS 33792    // 132 KB LDS; ceil(100000/33792) = 3 range passes
#define XS_LD 132     // padded leading dim for x tile in LDS

__device__ __forceinline__ unsigned short f2bf(float f) {   // RNE bf16
    unsigned int x = __float_as_uint(f);
    x += 0x7fffu + ((x >> 16) & 1u);
    return (unsigned short)(x >> 16);
}
__device__ __forceinline__ float bf2f(unsigned short u) {
    return __uint_as_float(((unsigned int)u) << 16);
}

// per-block LDS histogram over key ranges, dense flush (NO global atomics)
__global__ __launch_bounds__(TPB) void histcnt_k(const int* __restrict__ keys,
                                                 int* __restrict__ cnt, int e, int n) {
    __shared__ int bins[BINS];
    int b = blockIdx.x;
    int chunk = (e + gridDim.x - 1) / gridDim.x;
    int beg = b * chunk, end = min(e, beg + chunk);
    for (int rb = 0; rb < n; rb += BINS) {
        int hi = min(n - rb, BINS);
        for (int i = threadIdx.x; i < hi; i += TPB) bins[i] = 0;
        __syncthreads();
        for (int i = beg + threadIdx.x; i < end; i += TPB) {
            int k = keys[i] - rb;
            if ((unsigned)k < (unsigned)hi) atomicAdd(&bins[k], 1);
        }
        __syncthreads();
        for (int i = threadIdx.x; i < hi; i += TPB)
            cnt[(size_t)b * n + rb + i] = bins[i];
        __syncthreads();
    }
}

// sum count columns -> out_norm (run after histcnt on src)
__global__ void redout_k(const int* __restrict__ cnt, float* __restrict__ out_norm, int n) {
    int v = blockIdx.x * blockDim.x + threadIdx.x;
    if (v >= n) return;
    int s = 0;
    for (int b = 0; b < BH; ++b) s += cnt[(size_t)b * n + v];
    out_norm[v] = rsqrtf(fmaxf((float)s, 1.0f));
}

// in counts -> indeg + in_norm; rewrite cnt in place as per-block exclusive bases
__global__ void redin_k(int* __restrict__ cnt, float* __restrict__ in_norm,
                        int* __restrict__ indeg, int n) {
    int v = blockIdx.x * blockDim.x + threadIdx.x;
    if (v >= n) return;
    int run = 0;
    for (int b = 0; b < BH; ++b) {
        size_t idx = (size_t)b * n + v;
        int c = cnt[idx];
        cnt[idx] = run;
        run += c;
    }
    indeg[v] = run;
    in_norm[v] = rsqrtf(fmaxf((float)run, 1.0f));
}

// block sums of in-degree
__global__ void scanA(const int* __restrict__ indeg, int* __restrict__ bsum, int n) {
    int t = threadIdx.x;
    int i = blockIdx.x * 256 + t;
    int v = (i < n) ? indeg[i] : 0;
#pragma unroll
    for (int d = 1; d < 64; d <<= 1) v += __shfl_xor(v, d, 64);
    __shared__ int w4[4];
    if ((t & 63) == 0) w4[t >> 6] = v;
    __syncthreads();
    if (t == 0) bsum[blockIdx.x] = w4[0] + w4[1] + w4[2] + w4[3];
}

// exclusive scan of block sums (nb <= 512), writes rowptr[n] = E
__global__ void scanB(int* __restrict__ bsum, int nb, int* __restrict__ rowptr, int n) {
    __shared__ int s[512];
    int t = threadIdx.x;
    s[t] = (t < nb) ? bsum[t] : 0;
    __syncthreads();
    for (int d = 1; d < 512; d <<= 1) {
        int v = (t >= d) ? s[t - d] : 0;
        __syncthreads();
        s[t] += v;
        __syncthreads();
    }
    if (t < nb) bsum[t] = t ? s[t - 1] : 0;
    if (t == 0) rowptr[n] = s[nb - 1];
}

// per-block exclusive scan + block offset -> rowptr
__global__ void scanC(const int* __restrict__ indeg, const int* __restrict__ bsum,
                      int* __restrict__ rowptr, int n) {
    __shared__ int s[256];
    int t = threadIdx.x;
    int i = blockIdx.x * 256 + t;
    int v = (i < n) ? indeg[i] : 0;
    s[t] = v;
    __syncthreads();
    for (int d = 1; d < 256; d <<= 1) {
        int u = (t >= d) ? s[t - d] : 0;
        __syncthreads();
        s[t] += u;
        __syncthreads();
    }
    if (i < n) rowptr[i] = bsum[blockIdx.x] + s[t] - v;
}

// CSR fill: LDS cursors PRE-LOADED with the block's base column (streamed read),
// so the per-edge path does only ONE random read (rowptr[d], L2-resident 400KB).
__global__ __launch_bounds__(TPB) void fill2_k(const int* __restrict__ src, const int* __restrict__ dst,
                        const int* __restrict__ rowptr, const int* __restrict__ base,
                        int* __restrict__ csr, int e, int n) {
    __shared__ int cur[BINS];
    int b = blockIdx.x;
    int chunk = (e + gridDim.x - 1) / gridDim.x;
    int beg = b * chunk, end = min(e, beg + chunk);
    for (int rb = 0; rb < n; rb += BINS) {
        int hi = min(n - rb, BINS);
        for (int i = threadIdx.x; i < hi; i += TPB)
            cur[i] = base[(size_t)b * n + rb + i];
        __syncthreads();
        for (int i = beg + threadIdx.x; i < end; i += TPB) {
            int d = dst[i];
            int dl = d - rb;
            if ((unsigned)dl < (unsigned)hi) {
                int slot = rowptr[d] + atomicAdd(&cur[dl], 1);
                csr[slot] = src[i];
            }
        }
        __syncthreads();
    }
}

// h0[i][j] = bf16( out_norm[i] * (x[i] @ W1)[j] ); 64x64 tile, 4x4 per thread
__global__ __launch_bounds__(256) void gemm1_k(const float* __restrict__ x, const float* __restrict__ W1,
                        const float* __restrict__ out_norm, unsigned short* __restrict__ h0, int n) {
    __shared__ float xs[64 * XS_LD];
    __shared__ float Ws[IN_DIM * HID];
    int t = threadIdx.x;
    int row0 = blockIdx.x * 64;
#pragma unroll
    for (int j = 0; j < 8; ++j) {
        int f4 = t + j * 256;
        *(float4*)&Ws[f4 * 4] = ((const float4*)W1)[f4];
    }
#pragma unroll
    for (int j = 0; j < 8; ++j) {
        int f4 = t + j * 256;
        int r = f4 >> 5;
        int k = (f4 & 31) * 4;
        float4 v = (row0 + r < n) ? ((const float4*)x)[(size_t)(row0 + r) * 32 + (f4 & 31)]
                                  : make_float4(0.f, 0.f, 0.f, 0.f);
        *(float4*)&xs[r * XS_LD + k] = v;
    }
    __syncthreads();
    int rq = (t >> 4) * 4;
    int cq = (t & 15) * 4;
    float acc[4][4] = {};
    for (int k = 0; k < IN_DIM; k += 4) {
        float4 xr[4], wc[4];
#pragma unroll
        for (int i = 0; i < 4; ++i) xr[i] = *(const float4*)&xs[(rq + i) * XS_LD + k];
#pragma unroll
        for (int kk = 0; kk < 4; ++kk) wc[kk] = *(const float4*)&Ws[(k + kk) * HID + cq];
#pragma unroll
        for (int i = 0; i < 4; ++i) {
            float xv0 = xr[i].x, xv1 = xr[i].y, xv2 = xr[i].z, xv3 = xr[i].w;
            acc[i][0] += xv0 * wc[0].x + xv1 * wc[1].x + xv2 * wc[2].x + xv3 * wc[3].x;
            acc[i][1] += xv0 * wc[0].y + xv1 * wc[1].y + xv2 * wc[2].y + xv3 * wc[3].y;
            acc[i][2] += xv0 * wc[0].z + xv1 * wc[1].z + xv2 * wc[2].z + xv3 * wc[3].z;
            acc[i][3] += xv0 * wc[0].w + xv1 * wc[1].w + xv2 * wc[2].w + xv3 * wc[3].w;
        }
    }
#pragma unroll
    for (int i = 0; i < 4; ++i) {
        int row = row0 + rq + i;
        if (row < n) {
            float onn = out_norm[row];
            ushort4 o;
            o.x = f2bf(acc[i][0] * onn);
            o.y = f2bf(acc[i][1] * onn);
            o.z = f2bf(acc[i][2] * onn);
            o.w = f2bf(acc[i][3] * onn);
            *(ushort4*)&h0[(size_t)row * HID + cq] = o;
        }
    }
}

// wave per dst node: pull-aggregate bf16 h0 rows (f32 accum, 8-deep unroll),
// then relu/norm/bias + W2 projection via cross-lane reductions.
__global__ void agg1proj_k(const int* __restrict__ rowptr, const int* __restrict__ csr,
                           const unsigned short* __restrict__ h0, const float* __restrict__ in_norm,
                           const float* __restrict__ out_norm, const float* __restrict__ b1,
                           const float* __restrict__ W2, float* __restrict__ h2p, int n) {
    int wid = (blockIdx.x * blockDim.x + threadIdx.x) >> 6;
    int lane = threadIdx.x & 63;
    if (wid >= n) return;
    int beg = rowptr[wid], end = rowptr[wid + 1];
    float acc0 = 0.f, acc1 = 0.f, acc2 = 0.f, acc3 = 0.f;
    int j = beg;
    for (; j + 8 <= end; j += 8) {
        int s0 = csr[j],     s1 = csr[j + 1], s2 = csr[j + 2], s3 = csr[j + 3];
        int s4 = csr[j + 4], s5 = csr[j + 5], s6 = csr[j + 6], s7 = csr[j + 7];
        unsigned short a0 = h0[(size_t)s0 * HID + lane];
        unsigned short a1 = h0[(size_t)s1 * HID + lane];
        unsigned short a2 = h0[(size_t)s2 * HID + lane];
        unsigned short a3 = h0[(size_t)s3 * HID + lane];
        unsigned short a4 = h0[(size_t)s4 * HID + lane];
        unsigned short a5 = h0[(size_t)s5 * HID + lane];
        unsigned short a6 = h0[(size_t)s6 * HID + lane];
        unsigned short a7 = h0[(size_t)s7 * HID + lane];
        acc0 += bf2f(a0); acc1 += bf2f(a1); acc2 += bf2f(a2); acc3 += bf2f(a3);
        acc0 += bf2f(a4); acc1 += bf2f(a5); acc2 += bf2f(a6); acc3 += bf2f(a7);
    }
    if (j + 4 <= end) {
        int s0 = csr[j], s1 = csr[j + 1], s2 = csr[j + 2], s3 = csr[j + 3];
        acc0 += bf2f(h0[(size_t)s0 * HID + lane]);
        acc1 += bf2f(h0[(size_t)s1 * HID + lane]);
        acc2 += bf2f(h0[(size_t)s2 * HID + lane]);
        acc3 += bf2f(h0[(size_t)s3 * HID + lane]);
        j += 4;
    }
    for (; j < end; ++j) acc0 += bf2f(h0[(size_t)csr[j] * HID + lane]);
    float acc = (acc0 + acc1) + (acc2 + acc3);
    float v = fmaxf(acc * in_norm[wid] + b1[lane], 0.f);
    float onn = out_norm[wid];
    float res = 0.f;
#pragma unroll
    for (int c = 0; c < NC; ++c) {
        float p = v * W2[lane * NC + c];
        p += __shfl_xor(p, 1, 64);
        p += __shfl_xor(p, 2, 64);
        p += __shfl_xor(p, 4, 64);
        p += __shfl_xor(p, 8, 64);
        p += __shfl_xor(p, 16, 64);
        p += __shfl_xor(p, 32, 64);
        if (lane == c) res = p;
    }
    if (lane < NC) h2p[(size_t)wid * NC + lane] = onn * res;
}

// wave per dst node: pull-aggregate h2p rows (2-deep unroll), bias + softmax
__global__ void agg2smax_k(const int* __restrict__ rowptr, const int* __restrict__ csr,
                           const float* __restrict__ h2p, const float* __restrict__ in_norm,
                           const float* __restrict__ b2, float* __restrict__ out, int n) {
    int wid = (blockIdx.x * blockDim.x + threadIdx.x) >> 6;
    int lane = threadIdx.x & 63;
    if (wid >= n) return;
    int beg = rowptr[wid], end = rowptr[wid + 1];
    int c = lane & 7, e8 = lane >> 3;
    float acc0 = 0.f, acc1 = 0.f;
    int j = beg + e8;
    for (; j + 8 < end; j += 16) {
        int s0 = csr[j];
        int s1 = csr[j + 8];
        acc0 += h2p[(size_t)s0 * NC + c];
        acc1 += h2p[(size_t)s1 * NC + c];
    }
    for (; j < end; j += 8) acc0 += h2p[(size_t)csr[j] * NC + c];
    float acc = acc0 + acc1;
    acc += __shfl_xor(acc, 8, 64);
    acc += __shfl_xor(acc, 16, 64);
    acc += __shfl_xor(acc, 32, 64);
    float v = acc * in_norm[wid] + b2[c];
    float m = v;
    m = fmaxf(m, __shfl_xor(m, 1, 64));
    m = fmaxf(m, __shfl_xor(m, 2, 64));
    m = fmaxf(m, __shfl_xor(m, 4, 64));
    float ev = __expf(v - m);
    float s8 = ev;
    s8 += __shfl_xor(s8, 1, 64);
    s8 += __shfl_xor(s8, 2, 64);
    s8 += __shfl_xor(s8, 4, 64);
    if (e8 == 0) out[(size_t)wid * NC + c] = ev / s8;
}

extern "C" void kernel_launch(void* const* d_in, const int* in_sizes, int n_in,
                              void* d_out, int out_size, void* d_ws, size_t ws_size,
                              hipStream_t stream) {
    const float* x   = (const float*)d_in[0];
    const int*   src = (const int*)d_in[1];
    const int*   dst = (const int*)d_in[2];
    const float* W1  = (const float*)d_in[3];
    const float* b1  = (const float*)d_in[4];
    const float* W2  = (const float*)d_in[5];
    const float* b2  = (const float*)d_in[6];
    float* out = (float*)d_out;

    const int N = in_sizes[0] / IN_DIM;   // 100000
    const int E = in_sizes[1];            // 3200000
    const int NB = (N + 255) / 256;       // 391 (<= 512)

    // layout: small stuff, csr, then big region (cnt during build, h0+h2p after).
    float* ws = (float*)d_ws;
    float* out_norm = ws;                            // N
    float* in_norm  = ws + (size_t)N;                // N
    int*   indeg    = (int*)(ws + (size_t)2 * N);    // N
    int*   rowptr   = indeg + N;                     // N+1
    int*   bsum     = rowptr + (N + 1);              // 512
    int*   csr      = bsum + 512;                    // E
    int*   cnt      = csr + E;                       // BH*N ints (51.2 MB), dead after fill
    unsigned short* h0b = (unsigned short*)cnt;      // 64N bf16 (aliases cnt, 32N ints)
    float* h2p      = (float*)(cnt + (size_t)32 * N); // 8N floats (total 40N <= 128N ok)
    // total ~ 65 MB

    // 1. out-degree counts -> out_norm (cnt buffer pass 1)
    histcnt_k<<<BH, TPB, 0, stream>>>(src, cnt, E, N);
    redout_k<<<(N + 255) / 256, 256, 0, stream>>>(cnt, out_norm, N);
    // 2. in-degree counts -> indeg, in_norm, per-block bases (cnt buffer pass 2)
    histcnt_k<<<BH, TPB, 0, stream>>>(dst, cnt, E, N);
    redin_k<<<(N + 255) / 256, 256, 0, stream>>>(cnt, in_norm, indeg, N);
    // 3. rowptr = exclusive scan(indeg)
    scanA<<<NB, 256, 0, stream>>>(indeg, bsum, N);
    scanB<<<1, 512, 0, stream>>>(bsum, NB, rowptr, N);
    scanC<<<NB, 256, 0, stream>>>(indeg, bsum, rowptr, N);
    // 4. CSR fill (LDS cursors pre-loaded with bases; no global atomics)
    fill2_k<<<BH, TPB, 0, stream>>>(src, dst, rowptr, cnt, csr, E, N);
    // 5. dense compute (cnt region now reused as h0b/h2p)
    gemm1_k<<<(N + 63) / 64, 256, 0, stream>>>(x, W1, out_norm, h0b, N);
    agg1proj_k<<<(N + 3) / 4, 256, 0, stream>>>(rowptr, csr, h0b, in_norm, out_norm, b1, W2, h2p, N);
    agg2smax_k<<<(N + 3) / 4, 256, 0, stream>>>(rowptr, csr, h2p, in_norm, b2, out, N);
}